// Round 3
// baseline (1825.448 us; speedup 1.0000x reference)
//
#include <hip/hip_runtime.h>

// LightGCN on MI355X, round 3.
// r1 evidence: atomic-scatter SpMM -> 3.2 GB HBM writes/dispatch (line ampl).
// r2 evidence: CSR build scatter wrote 198 MB (8B random writes into 25.6 MB
// window -> 64B line per edge); single-block 100k scan serial on 1 CU.
// r3: two-level bucketed counting sort (pass A: 391 cursor-sequential coarse
// buckets; pass B: per-bucket LDS sort into 65KB L2-resident window), plus
// batch-filtered UI aggregation fused with the final dot (only <=4096 of 50k
// user rows are ever read).

#define MM 100000
#define UU 50000
#define DD 64
#define RPB 256          // rows per bucket (shift 8)
#define BSH 8

__device__ __forceinline__ float row_gather(const int* __restrict__ rp_beg_end_unused,
                                            int beg, int end,
                                            const int2* __restrict__ edges,
                                            const float* __restrict__ x, int lane) {
    float sum = 0.f;
    for (int e = beg; e < end; e += 64) {
        int idx = e + lane;
        int2 ev = (idx < end) ? edges[idx] : make_int2(0, 0);
        int cnt = min(64, end - e);
        int j = 0;
        for (; j + 4 <= cnt; j += 4) {
            int d0 = __shfl(ev.x, j,     64), d1 = __shfl(ev.x, j + 1, 64);
            int d2 = __shfl(ev.x, j + 2, 64), d3 = __shfl(ev.x, j + 3, 64);
            float v0 = __int_as_float(__shfl(ev.y, j,     64));
            float v1 = __int_as_float(__shfl(ev.y, j + 1, 64));
            float v2 = __int_as_float(__shfl(ev.y, j + 2, 64));
            float v3 = __int_as_float(__shfl(ev.y, j + 3, 64));
            float x0 = x[(size_t)d0 * DD + lane];
            float x1 = x[(size_t)d1 * DD + lane];
            float x2 = x[(size_t)d2 * DD + lane];
            float x3 = x[(size_t)d3 * DD + lane];
            sum = fmaf(v0, x0, sum);
            sum = fmaf(v1, x1, sum);
            sum = fmaf(v2, x2, sum);
            sum = fmaf(v3, x3, sum);
        }
        for (; j < cnt; j++) {
            int d = __shfl(ev.x, j, 64);
            float v = __int_as_float(__shfl(ev.y, j, 64));
            sum = fmaf(v, x[(size_t)d * DD + lane], sum);
        }
    }
    return sum;
}

// ---- CSR build: two-level counting sort ----

// per-block LDS histogram of coarse buckets; filter != nullptr drops edges
// whose src is not in the sampled-user set.
__global__ void bucket_hist(const int* __restrict__ src, int* __restrict__ bcnt,
                            int nnz, int nb, int chunk,
                            const unsigned char* __restrict__ filter) {
    extern __shared__ int lcnt[];
    for (int i = threadIdx.x; i < nb; i += blockDim.x) lcnt[i] = 0;
    __syncthreads();
    int start = blockIdx.x * chunk;
    int end = min(nnz, start + chunk);
    for (int i = start + threadIdx.x; i < end; i += blockDim.x) {
        int s = src[i];
        if (filter && !filter[s]) continue;
        atomicAdd(&lcnt[s >> BSH], 1);
    }
    __syncthreads();
    for (int i = threadIdx.x; i < nb; i += blockDim.x)
        if (lcnt[i]) atomicAdd(&bcnt[i], lcnt[i]);
}

// single small block: exclusive scan of nb (<512) bucket counts
__global__ void small_scan(const int* __restrict__ cnt, int* __restrict__ base,
                           int* __restrict__ cursor, int nb) {
    __shared__ int sh[512];
    int t = threadIdx.x;
    int v = (t < nb) ? cnt[t] : 0;
    sh[t] = v;
    __syncthreads();
    for (int off = 1; off < 512; off <<= 1) {
        int u = (t >= off) ? sh[t - off] : 0;
        __syncthreads();
        sh[t] += u;
        __syncthreads();
    }
    int excl = sh[t] - v;
    if (t < nb) { base[t] = excl; cursor[t] = excl; }
    if (t == nb - 1) base[nb] = sh[t];
}

// pass A: scatter to coarse bucket (cursor-sequential writes, line-friendly)
__global__ void bucket_scatter(const int* __restrict__ src, const int* __restrict__ dst,
                               const float* __restrict__ val, int* __restrict__ cursor,
                               int2* __restrict__ tmpDV, unsigned char* __restrict__ tmpS,
                               int nnz, const unsigned char* __restrict__ filter) {
    int i = blockIdx.x * blockDim.x + threadIdx.x;
    if (i >= nnz) return;
    int s = src[i];
    if (filter && !filter[s]) return;
    int pos = atomicAdd(&cursor[s >> BSH], 1);
    tmpDV[pos] = make_int2(dst[i], __float_as_int(val[i]));
    tmpS[pos] = (unsigned char)(s & (RPB - 1));
}

// pass B: one block per bucket; LDS row-hist -> LDS scan -> LDS-cursor scatter
// into the bucket's contiguous (L2-resident) output window. Writes row_ptr.
__global__ void bucket_sort_b(const int* __restrict__ base, const unsigned char* __restrict__ tmpS,
                              const int2* __restrict__ tmpDV, int2* __restrict__ edges,
                              int* __restrict__ rp, int n_rows, int nb) {
    __shared__ int cnt[RPB];
    __shared__ int cur[RPB];
    __shared__ int sc[RPB];
    int b = blockIdx.x, t = threadIdx.x;
    int row0 = b << BSH;
    int beg = base[b], end = base[b + 1];
    if (b == 0 && t == 0) rp[n_rows] = base[nb];
    cnt[t] = 0;
    __syncthreads();
    for (int i = beg + t; i < end; i += blockDim.x)
        atomicAdd(&cnt[tmpS[i]], 1);
    __syncthreads();
    int v = cnt[t];
    sc[t] = v;
    __syncthreads();
    for (int off = 1; off < RPB; off <<= 1) {
        int u = (t >= off) ? sc[t - off] : 0;
        __syncthreads();
        sc[t] += u;
        __syncthreads();
    }
    int excl = sc[t] - v;
    int r = row0 + t;
    if (r < n_rows) rp[r] = beg + excl;
    cur[t] = beg + excl;
    __syncthreads();
    for (int i = beg + t; i < end; i += blockDim.x) {
        int s = tmpS[i];
        int2 dv = tmpDV[i];
        int pos = atomicAdd(&cur[s], 1);
        edges[pos] = dv;
    }
}

// ---- propagation SpMM: one wave per row, lane = dim ----
template <bool WRITE_Y, bool INIT_ACC>
__global__ void spmm_csr_kernel(const int* __restrict__ rp, const int2* __restrict__ edges,
                                const float* __restrict__ x, float* __restrict__ y,
                                float* __restrict__ acc, const float* __restrict__ att,
                                int layer, int n_rows) {
    int w = (blockIdx.x * blockDim.x + threadIdx.x) >> 6;
    int lane = threadIdx.x & 63;
    if (w >= n_rows) return;
    float sum = row_gather(nullptr, rp[w], rp[w + 1], edges, x, lane);
    sum *= att[layer];
    size_t o = (size_t)w * DD + lane;
    if (WRITE_Y) y[o] = sum;
    if (INIT_ACC) acc[o] = x[o] + sum;   // layer 1: acc = e0 + e1
    else          acc[o] += sum;
}

__global__ void set_bitmap(const int* __restrict__ users, unsigned char* __restrict__ bm, int B) {
    int i = blockIdx.x * blockDim.x + threadIdx.x;
    if (i < B) bm[users[i]] = 1;
}

// fused UI-SpMM + pair dot: one wave per batch element.
// gamma[b] = (1/16) * sum_lane( (sum_{e in row users[b]} val*acc[dst]) * acc[items[b]] )
__global__ void user_dot_kernel(const int* __restrict__ users, const int* __restrict__ items,
                                const int* __restrict__ rp, const int2* __restrict__ edges,
                                const float* __restrict__ acc, float* __restrict__ out, int B) {
    int w = (blockIdx.x * blockDim.x + threadIdx.x) >> 6;
    int lane = threadIdx.x & 63;
    if (w >= B) return;
    int u = users[w];
    float sum = row_gather(nullptr, rp[u], rp[u + 1], edges, acc, lane);
    float p = sum * acc[(size_t)items[w] * DD + lane];
    #pragma unroll
    for (int m = 32; m >= 1; m >>= 1) p += __shfl_xor(p, m, 64);
    if (lane == 0) out[w] = p * 0.0625f;
}

extern "C" void kernel_launch(void* const* d_in, const int* in_sizes, int n_in,
                              void* d_out, int out_size, void* d_ws, size_t ws_size,
                              hipStream_t stream) {
    const int*   users    = (const int*)d_in[0];
    const int*   items    = (const int*)d_in[1];
    const int*   ii_src   = (const int*)d_in[2];
    const int*   ii_dst   = (const int*)d_in[3];
    const float* ii_val   = (const float*)d_in[4];
    const int*   ui_src   = (const int*)d_in[5];
    const int*   ui_dst   = (const int*)d_in[6];
    const float* ui_val   = (const float*)d_in[7];
    const float* item_emb = (const float*)d_in[8];
    const float* att      = (const float*)d_in[9];

    const int E_ii = in_sizes[2];
    const int E_ui = in_sizes[5];
    const int B    = in_sizes[0];
    const int NB_ii = (MM + RPB - 1) / RPB;   // 391
    const int NB_ui = (UU + RPB - 1) / RPB;   // 196

    const size_t md = (size_t)MM * DD;        // 6.4M floats = 25.6 MB
    char* w = (char*)d_ws;
    float* buf0 = (float*)(w);                          // layer buf; overlay: tmpDV
    float* buf1 = (float*)(w + 25600000);               // layer buf; overlay: tmpS
    float* acc  = (float*)(w + 51200000);               // e0+e1+e2+e3
    int2*  edges = (int2*)(w + 76800000);               // sorted (dst,val), 3.2M cap
    int*   rp    = (int*)(w + 102400000);               // row_ptr, MM+1 cap
    int*   bcnt  = rp + MM + 2;
    int*   bbase = bcnt + 512;
    int*   bcur  = bbase + 514;
    unsigned char* bitmap = (unsigned char*)(bcur + 512);  // UU bytes

    int2*          tmpDV = (int2*)buf0;
    unsigned char* tmpS  = (unsigned char*)buf1;

    const int TB = 256;

    // ---- build item-item CSR ----
    hipMemsetAsync(bcnt, 0, 512 * sizeof(int), stream);
    {
        int chunk = (E_ii + 255) / 256;
        bucket_hist<<<256, TB, NB_ii * sizeof(int), stream>>>(ii_src, bcnt, E_ii, NB_ii, chunk, nullptr);
    }
    small_scan<<<1, 512, 0, stream>>>(bcnt, bbase, bcur, NB_ii);
    bucket_scatter<<<(E_ii + TB - 1) / TB, TB, 0, stream>>>(ii_src, ii_dst, ii_val, bcur,
                                                            tmpDV, tmpS, E_ii, nullptr);
    bucket_sort_b<<<NB_ii, RPB, 0, stream>>>(bbase, tmpS, tmpDV, edges, rp, MM, NB_ii);

    // ---- 3 propagation layers (acc fused; layer1 inits acc = e0+e1) ----
    const int ii_blocks = (MM * 64 + TB - 1) / TB;
    spmm_csr_kernel<true,  true ><<<ii_blocks, TB, 0, stream>>>(rp, edges, item_emb, buf0, acc, att, 0, MM);
    spmm_csr_kernel<true,  false><<<ii_blocks, TB, 0, stream>>>(rp, edges, buf0,     buf1, acc, att, 1, MM);
    spmm_csr_kernel<false, false><<<ii_blocks, TB, 0, stream>>>(rp, edges, buf1, (float*)nullptr, acc, att, 2, MM);

    // ---- build batch-filtered user-item CSR (buf0/buf1 free again) ----
    hipMemsetAsync(bitmap, 0, UU, stream);
    set_bitmap<<<(B + TB - 1) / TB, TB, 0, stream>>>(users, bitmap, B);
    hipMemsetAsync(bcnt, 0, 512 * sizeof(int), stream);
    {
        int chunk = (E_ui + 255) / 256;
        bucket_hist<<<256, TB, NB_ui * sizeof(int), stream>>>(ui_src, bcnt, E_ui, NB_ui, chunk, bitmap);
    }
    small_scan<<<1, 512, 0, stream>>>(bcnt, bbase, bcur, NB_ui);
    bucket_scatter<<<(E_ui + TB - 1) / TB, TB, 0, stream>>>(ui_src, ui_dst, ui_val, bcur,
                                                            tmpDV, tmpS, E_ui, bitmap);
    bucket_sort_b<<<NB_ui, RPB, 0, stream>>>(bbase, tmpS, tmpDV, edges, rp, UU, NB_ui);

    // ---- fused user aggregation + pair dot ----
    user_dot_kernel<<<(B * 64 + TB - 1) / TB, TB, 0, stream>>>(users, items, rp, edges, acc,
                                                               (float*)d_out, B);
}

// Round 4
// 733.605 us; speedup vs baseline: 2.4883x; 2.4883x over previous
//
#include <hip/hip_runtime.h>

// LightGCN on MI355X, round 4.
// r1: atomic-scatter SpMM -> 3.2 GB HBM writes/dispatch. -> gather CSR SpMM.
// r2: per-row (100k-cursor) scatter: 198 MB writes (8B random -> 64B line), 260 us.
// r3: 391-coarse-bucket per-EDGE atomic cursors -> 3.2M atomics on 391 addrs ->
//     contention-serialized, 1109 us. WRONG FIX.
// r4: block-level reservation: LDS hist per 16k-edge chunk, ONE global atomic
//     per (block,bucket) to reserve a contiguous run, LDS-cursor scatter.
//     ~77k atomics total, per-block runs fill cache lines.

#define MM 100000
#define UU 50000
#define DD 64
#define RPB 256          // rows per coarse bucket
#define BSH 8
#define NBMAX 400
#define CHUNK 16384

// ---- gather primitive: one wave owns a row, lane = dim ----
__device__ __forceinline__ float row_gather(int beg, int end,
                                            const int2* __restrict__ edges,
                                            const float* __restrict__ x, int lane) {
    float sum = 0.f;
    for (int e = beg; e < end; e += 64) {
        int idx = e + lane;
        int2 ev = (idx < end) ? edges[idx] : make_int2(0, 0);
        int cnt = min(64, end - e);
        int j = 0;
        for (; j + 4 <= cnt; j += 4) {
            int d0 = __shfl(ev.x, j,     64), d1 = __shfl(ev.x, j + 1, 64);
            int d2 = __shfl(ev.x, j + 2, 64), d3 = __shfl(ev.x, j + 3, 64);
            float v0 = __int_as_float(__shfl(ev.y, j,     64));
            float v1 = __int_as_float(__shfl(ev.y, j + 1, 64));
            float v2 = __int_as_float(__shfl(ev.y, j + 2, 64));
            float v3 = __int_as_float(__shfl(ev.y, j + 3, 64));
            float x0 = x[(size_t)d0 * DD + lane];
            float x1 = x[(size_t)d1 * DD + lane];
            float x2 = x[(size_t)d2 * DD + lane];
            float x3 = x[(size_t)d3 * DD + lane];
            sum = fmaf(v0, x0, sum);
            sum = fmaf(v1, x1, sum);
            sum = fmaf(v2, x2, sum);
            sum = fmaf(v3, x3, sum);
        }
        for (; j < cnt; j++) {
            int d = __shfl(ev.x, j, 64);
            float v = __int_as_float(__shfl(ev.y, j, 64));
            sum = fmaf(v, x[(size_t)d * DD + lane], sum);
        }
    }
    return sum;
}

// ---- CSR build ----

// global coarse-bucket histogram (LDS-aggregated)
__global__ void bucket_hist(const int* __restrict__ src, int* __restrict__ bcnt,
                            int nnz, int nb, int chunk,
                            const unsigned char* __restrict__ filter) {
    extern __shared__ int lcnt[];
    for (int i = threadIdx.x; i < nb; i += blockDim.x) lcnt[i] = 0;
    __syncthreads();
    int start = blockIdx.x * chunk;
    int end = min(nnz, start + chunk);
    for (int i = start + threadIdx.x; i < end; i += blockDim.x) {
        int s = src[i];
        if (filter && !filter[s]) continue;
        atomicAdd(&lcnt[s >> BSH], 1);
    }
    __syncthreads();
    for (int i = threadIdx.x; i < nb; i += blockDim.x)
        if (lcnt[i]) atomicAdd(&bcnt[i], lcnt[i]);
}

// exclusive scan of nb (<512) bucket counts
__global__ void small_scan(const int* __restrict__ cnt, int* __restrict__ base,
                           int* __restrict__ cursor, int nb) {
    __shared__ int sh[512];
    int t = threadIdx.x;
    int v = (t < nb) ? cnt[t] : 0;
    sh[t] = v;
    __syncthreads();
    for (int off = 1; off < 512; off <<= 1) {
        int u = (t >= off) ? sh[t - off] : 0;
        __syncthreads();
        sh[t] += u;
        __syncthreads();
    }
    int excl = sh[t] - v;
    if (t < nb) { base[t] = excl; cursor[t] = excl; }
    if (t == nb - 1) base[nb] = sh[t];
}

// pass A: block-level reservation scatter into coarse buckets.
// tmp.x = dst | (src&255)<<17  (dst < 2^17), tmp.y = val bits.
__global__ void pass_a(const int* __restrict__ src, const int* __restrict__ dst,
                       const float* __restrict__ val, int* __restrict__ bcur,
                       int2* __restrict__ tmp, int nnz, int nb,
                       const unsigned char* __restrict__ filter) {
    __shared__ int lcnt[NBMAX];
    __shared__ int lcur[NBMAX];
    int t = threadIdx.x;
    for (int i = t; i < nb; i += blockDim.x) lcnt[i] = 0;
    __syncthreads();
    int beg = blockIdx.x * CHUNK, end = min(nnz, beg + CHUNK);
    for (int i = beg + t; i < end; i += blockDim.x) {
        int s = src[i];
        if (filter && !filter[s]) continue;
        atomicAdd(&lcnt[s >> BSH], 1);
    }
    __syncthreads();
    for (int i = t; i < nb; i += blockDim.x) {
        int c = lcnt[i];
        lcur[i] = c ? atomicAdd(&bcur[i], c) : 0;   // ONE reservation per (block,bucket)
    }
    __syncthreads();
    for (int i = beg + t; i < end; i += blockDim.x) {
        int s = src[i];
        if (filter && !filter[s]) continue;
        int pos = atomicAdd(&lcur[s >> BSH], 1);    // LDS cursor
        tmp[pos] = make_int2(dst[i] | ((s & (RPB - 1)) << 17), __float_as_int(val[i]));
    }
}

// pass B: one block per bucket; LDS row-hist -> LDS scan -> LDS-cursor scatter
// into the bucket's contiguous window. Also writes row_ptr.
__global__ void pass_b(const int* __restrict__ base, const int2* __restrict__ tmp,
                       int2* __restrict__ edges, int* __restrict__ rp,
                       int n_rows, int nb) {
    __shared__ int cnt[RPB];
    __shared__ int cur[RPB];
    __shared__ int sc[RPB];
    int b = blockIdx.x, t = threadIdx.x;
    int beg = base[b], end = base[b + 1];
    if (b == 0 && t == 0) rp[n_rows] = base[nb];
    cnt[t] = 0;
    __syncthreads();
    for (int i = beg + t; i < end; i += blockDim.x)
        atomicAdd(&cnt[tmp[i].x >> 17], 1);
    __syncthreads();
    int v = cnt[t];
    sc[t] = v;
    __syncthreads();
    for (int off = 1; off < RPB; off <<= 1) {
        int u = (t >= off) ? sc[t - off] : 0;
        __syncthreads();
        sc[t] += u;
        __syncthreads();
    }
    int excl = sc[t] - v;
    int r = (b << BSH) + t;
    if (r < n_rows) rp[r] = beg + excl;
    cur[t] = beg + excl;
    __syncthreads();
    for (int i = beg + t; i < end; i += blockDim.x) {
        int2 e = tmp[i];
        int s = e.x >> 17;
        int pos = atomicAdd(&cur[s], 1);
        edges[pos] = make_int2(e.x & 0x1FFFF, e.y);
    }
}

// ---- propagation SpMM ----
template <bool WRITE_Y, bool INIT_ACC>
__global__ void spmm_csr_kernel(const int* __restrict__ rp, const int2* __restrict__ edges,
                                const float* __restrict__ x, float* __restrict__ y,
                                float* __restrict__ acc, const float* __restrict__ att,
                                int layer, int n_rows) {
    int w = (blockIdx.x * blockDim.x + threadIdx.x) >> 6;
    int lane = threadIdx.x & 63;
    if (w >= n_rows) return;
    float sum = row_gather(rp[w], rp[w + 1], edges, x, lane);
    sum *= att[layer];
    size_t o = (size_t)w * DD + lane;
    if (WRITE_Y) y[o] = sum;
    if (INIT_ACC) acc[o] = x[o] + sum;   // layer 1: acc = e0 + e1
    else          acc[o] += sum;
}

__global__ void set_bitmap(const int* __restrict__ users, unsigned char* __restrict__ bm, int B) {
    int i = blockIdx.x * blockDim.x + threadIdx.x;
    if (i < B) bm[users[i]] = 1;
}

// fused UI-SpMM + pair dot: one wave per batch element
__global__ void user_dot_kernel(const int* __restrict__ users, const int* __restrict__ items,
                                const int* __restrict__ rp, const int2* __restrict__ edges,
                                const float* __restrict__ acc, float* __restrict__ out, int B) {
    int w = (blockIdx.x * blockDim.x + threadIdx.x) >> 6;
    int lane = threadIdx.x & 63;
    if (w >= B) return;
    int u = users[w];
    float sum = row_gather(rp[u], rp[u + 1], edges, acc, lane);
    float p = sum * acc[(size_t)items[w] * DD + lane];
    #pragma unroll
    for (int m = 32; m >= 1; m >>= 1) p += __shfl_xor(p, m, 64);
    if (lane == 0) out[w] = p * 0.0625f;   // (1/4 mean) each side
}

extern "C" void kernel_launch(void* const* d_in, const int* in_sizes, int n_in,
                              void* d_out, int out_size, void* d_ws, size_t ws_size,
                              hipStream_t stream) {
    const int*   users    = (const int*)d_in[0];
    const int*   items    = (const int*)d_in[1];
    const int*   ii_src   = (const int*)d_in[2];
    const int*   ii_dst   = (const int*)d_in[3];
    const float* ii_val   = (const float*)d_in[4];
    const int*   ui_src   = (const int*)d_in[5];
    const int*   ui_dst   = (const int*)d_in[6];
    const float* ui_val   = (const float*)d_in[7];
    const float* item_emb = (const float*)d_in[8];
    const float* att      = (const float*)d_in[9];

    const int E_ii = in_sizes[2];
    const int E_ui = in_sizes[5];
    const int B    = in_sizes[0];
    const int NB_ii = (MM + RPB - 1) / RPB;   // 391
    const int NB_ui = (UU + RPB - 1) / RPB;   // 196

    char* w = (char*)d_ws;
    float* buf0 = (float*)(w);                          // layer buf; overlay: tmp
    float* buf1 = (float*)(w + 25600000);               // layer buf
    float* acc  = (float*)(w + 51200000);               // e0+e1+e2+e3
    int2*  edges = (int2*)(w + 76800000);               // sorted (dst,val)
    int*   rp    = (int*)(w + 102400000);               // row_ptr, MM+1
    int*   bcnt  = rp + MM + 2;
    int*   bbase = bcnt + 512;
    int*   bcur  = bbase + 514;
    unsigned char* bitmap = (unsigned char*)(bcur + 512);  // UU bytes

    int2* tmp = (int2*)buf0;    // coarse-bucketed edges (free during builds)

    const int TB = 256;

    // ---- build item-item CSR ----
    hipMemsetAsync(bcnt, 0, 512 * sizeof(int), stream);
    {
        int chunk = (E_ii + 255) / 256;
        bucket_hist<<<256, TB, NB_ii * sizeof(int), stream>>>(ii_src, bcnt, E_ii, NB_ii, chunk, nullptr);
    }
    small_scan<<<1, 512, 0, stream>>>(bcnt, bbase, bcur, NB_ii);
    pass_a<<<(E_ii + CHUNK - 1) / CHUNK, TB, 0, stream>>>(ii_src, ii_dst, ii_val, bcur, tmp, E_ii, NB_ii, nullptr);
    pass_b<<<NB_ii, RPB, 0, stream>>>(bbase, tmp, edges, rp, MM, NB_ii);

    // ---- 3 propagation layers (acc fused; layer1 inits acc = e0+e1) ----
    const int ii_blocks = (MM * 64 + TB - 1) / TB;
    spmm_csr_kernel<true,  true ><<<ii_blocks, TB, 0, stream>>>(rp, edges, item_emb, buf0, acc, att, 0, MM);
    spmm_csr_kernel<true,  false><<<ii_blocks, TB, 0, stream>>>(rp, edges, buf0,     buf1, acc, att, 1, MM);
    spmm_csr_kernel<false, false><<<ii_blocks, TB, 0, stream>>>(rp, edges, buf1, (float*)nullptr, acc, att, 2, MM);

    // ---- build batch-filtered user-item CSR (buf0 free again) ----
    hipMemsetAsync(bitmap, 0, UU, stream);
    set_bitmap<<<(B + TB - 1) / TB, TB, 0, stream>>>(users, bitmap, B);
    hipMemsetAsync(bcnt, 0, 512 * sizeof(int), stream);
    {
        int chunk = (E_ui + 255) / 256;
        bucket_hist<<<256, TB, NB_ui * sizeof(int), stream>>>(ui_src, bcnt, E_ui, NB_ui, chunk, bitmap);
    }
    small_scan<<<1, 512, 0, stream>>>(bcnt, bbase, bcur, NB_ui);
    pass_a<<<(E_ui + CHUNK - 1) / CHUNK, TB, 0, stream>>>(ui_src, ui_dst, ui_val, bcur, tmp, E_ui, NB_ui, bitmap);
    pass_b<<<NB_ui, RPB, 0, stream>>>(bbase, tmp, edges, rp, UU, NB_ui);

    // ---- fused user aggregation + pair dot ----
    user_dot_kernel<<<(B * 64 + TB - 1) / TB, TB, 0, stream>>>(users, items, rp, edges, acc,
                                                               (float*)d_out, B);
}

// Round 5
// 612.558 us; speedup vs baseline: 2.9800x; 1.1976x over previous
//
#include <hip/hip_runtime.h>

// LightGCN on MI355X, round 5.
// r1: atomic-scatter SpMM -> 3.2 GB HBM writes. -> gather CSR SpMM.
// r2: per-row cursor scatter: 198 MB writes, 260 us.
// r3: 391-bucket per-edge atomics -> contention, 1109 us.
// r4: block-level reservation build -> 733 us total; 3 spmm layers now dominate
//     (112 us, 368 MB fetch each: random dst => each XCD pulls whole x table).
// r5: bf16 x-tables (fp32 accumulate, RN store): halves gather footprint.
//     acc + final dot stay fp32. pass_a CHUNK 16384->8192 (196 blocks left CUs idle).

#define MM 100000
#define UU 50000
#define DD 64
#define RPB 256          // rows per coarse bucket
#define BSH 8
#define NBMAX 400
#define CHUNK 8192

__device__ __forceinline__ float bf2f(unsigned short u) {
    return __uint_as_float(((unsigned int)u) << 16);
}
__device__ __forceinline__ unsigned short f2bf(float f) {
    unsigned int b = __float_as_uint(f);
    b += 0x7FFF + ((b >> 16) & 1);          // round-to-nearest-even
    return (unsigned short)(b >> 16);
}

// ---- gather primitive over bf16 table: one wave owns a row, lane = dim ----
__device__ __forceinline__ float row_gather_bf16(int beg, int end,
                                                 const int2* __restrict__ edges,
                                                 const unsigned short* __restrict__ xb, int lane) {
    float sum = 0.f;
    for (int e = beg; e < end; e += 64) {
        int idx = e + lane;
        int2 ev = (idx < end) ? edges[idx] : make_int2(0, 0);
        int cnt = min(64, end - e);
        int j = 0;
        for (; j + 4 <= cnt; j += 4) {
            int d0 = __shfl(ev.x, j,     64), d1 = __shfl(ev.x, j + 1, 64);
            int d2 = __shfl(ev.x, j + 2, 64), d3 = __shfl(ev.x, j + 3, 64);
            float v0 = __int_as_float(__shfl(ev.y, j,     64));
            float v1 = __int_as_float(__shfl(ev.y, j + 1, 64));
            float v2 = __int_as_float(__shfl(ev.y, j + 2, 64));
            float v3 = __int_as_float(__shfl(ev.y, j + 3, 64));
            float x0 = bf2f(xb[(size_t)d0 * DD + lane]);
            float x1 = bf2f(xb[(size_t)d1 * DD + lane]);
            float x2 = bf2f(xb[(size_t)d2 * DD + lane]);
            float x3 = bf2f(xb[(size_t)d3 * DD + lane]);
            sum = fmaf(v0, x0, sum);
            sum = fmaf(v1, x1, sum);
            sum = fmaf(v2, x2, sum);
            sum = fmaf(v3, x3, sum);
        }
        for (; j < cnt; j++) {
            int d = __shfl(ev.x, j, 64);
            float v = __int_as_float(__shfl(ev.y, j, 64));
            sum = fmaf(v, bf2f(xb[(size_t)d * DD + lane]), sum);
        }
    }
    return sum;
}

// fp32 gather (user-side final aggregation keeps full precision)
__device__ __forceinline__ float row_gather_f32(int beg, int end,
                                                const int2* __restrict__ edges,
                                                const float* __restrict__ x, int lane) {
    float sum = 0.f;
    for (int e = beg; e < end; e += 64) {
        int idx = e + lane;
        int2 ev = (idx < end) ? edges[idx] : make_int2(0, 0);
        int cnt = min(64, end - e);
        for (int j = 0; j < cnt; j++) {
            int d = __shfl(ev.x, j, 64);
            float v = __int_as_float(__shfl(ev.y, j, 64));
            sum = fmaf(v, x[(size_t)d * DD + lane], sum);
        }
    }
    return sum;
}

// ---- CSR build (two-level counting sort, r4 structure) ----

__global__ void bucket_hist(const int* __restrict__ src, int* __restrict__ bcnt,
                            int nnz, int nb, int chunk,
                            const unsigned char* __restrict__ filter) {
    extern __shared__ int lcnt[];
    for (int i = threadIdx.x; i < nb; i += blockDim.x) lcnt[i] = 0;
    __syncthreads();
    int start = blockIdx.x * chunk;
    int end = min(nnz, start + chunk);
    for (int i = start + threadIdx.x; i < end; i += blockDim.x) {
        int s = src[i];
        if (filter && !filter[s]) continue;
        atomicAdd(&lcnt[s >> BSH], 1);
    }
    __syncthreads();
    for (int i = threadIdx.x; i < nb; i += blockDim.x)
        if (lcnt[i]) atomicAdd(&bcnt[i], lcnt[i]);
}

__global__ void small_scan(const int* __restrict__ cnt, int* __restrict__ base,
                           int* __restrict__ cursor, int nb) {
    __shared__ int sh[512];
    int t = threadIdx.x;
    int v = (t < nb) ? cnt[t] : 0;
    sh[t] = v;
    __syncthreads();
    for (int off = 1; off < 512; off <<= 1) {
        int u = (t >= off) ? sh[t - off] : 0;
        __syncthreads();
        sh[t] += u;
        __syncthreads();
    }
    int excl = sh[t] - v;
    if (t < nb) { base[t] = excl; cursor[t] = excl; }
    if (t == nb - 1) base[nb] = sh[t];
}

// pass A: block-level reservation scatter into coarse buckets.
__global__ void pass_a(const int* __restrict__ src, const int* __restrict__ dst,
                       const float* __restrict__ val, int* __restrict__ bcur,
                       int2* __restrict__ tmp, int nnz, int nb,
                       const unsigned char* __restrict__ filter) {
    __shared__ int lcnt[NBMAX];
    __shared__ int lcur[NBMAX];
    int t = threadIdx.x;
    for (int i = t; i < nb; i += blockDim.x) lcnt[i] = 0;
    __syncthreads();
    int beg = blockIdx.x * CHUNK, end = min(nnz, beg + CHUNK);
    for (int i = beg + t; i < end; i += blockDim.x) {
        int s = src[i];
        if (filter && !filter[s]) continue;
        atomicAdd(&lcnt[s >> BSH], 1);
    }
    __syncthreads();
    for (int i = t; i < nb; i += blockDim.x) {
        int c = lcnt[i];
        lcur[i] = c ? atomicAdd(&bcur[i], c) : 0;   // ONE reservation per (block,bucket)
    }
    __syncthreads();
    for (int i = beg + t; i < end; i += blockDim.x) {
        int s = src[i];
        if (filter && !filter[s]) continue;
        int pos = atomicAdd(&lcur[s >> BSH], 1);    // LDS cursor
        tmp[pos] = make_int2(dst[i] | ((s & (RPB - 1)) << 17), __float_as_int(val[i]));
    }
}

// pass B: per-bucket LDS sort into contiguous window; writes row_ptr.
__global__ void pass_b(const int* __restrict__ base, const int2* __restrict__ tmp,
                       int2* __restrict__ edges, int* __restrict__ rp,
                       int n_rows, int nb) {
    __shared__ int cnt[RPB];
    __shared__ int cur[RPB];
    __shared__ int sc[RPB];
    int b = blockIdx.x, t = threadIdx.x;
    int beg = base[b], end = base[b + 1];
    if (b == 0 && t == 0) rp[n_rows] = base[nb];
    cnt[t] = 0;
    __syncthreads();
    for (int i = beg + t; i < end; i += blockDim.x)
        atomicAdd(&cnt[tmp[i].x >> 17], 1);
    __syncthreads();
    int v = cnt[t];
    sc[t] = v;
    __syncthreads();
    for (int off = 1; off < RPB; off <<= 1) {
        int u = (t >= off) ? sc[t - off] : 0;
        __syncthreads();
        sc[t] += u;
        __syncthreads();
    }
    int excl = sc[t] - v;
    int r = (b << BSH) + t;
    if (r < n_rows) rp[r] = beg + excl;
    cur[t] = beg + excl;
    __syncthreads();
    for (int i = beg + t; i < end; i += blockDim.x) {
        int2 e = tmp[i];
        int s = e.x >> 17;
        int pos = atomicAdd(&cur[s], 1);
        edges[pos] = make_int2(e.x & 0x1FFFF, e.y);
    }
}

// ---- fp32 -> bf16 table conversion ----
__global__ void conv_bf16(const float4* __restrict__ in, ushort4* __restrict__ out, int n4) {
    int i = blockIdx.x * blockDim.x + threadIdx.x;
    if (i >= n4) return;
    float4 v = in[i];
    ushort4 o;
    o.x = f2bf(v.x); o.y = f2bf(v.y); o.z = f2bf(v.z); o.w = f2bf(v.w);
    out[i] = o;
}

// ---- propagation SpMM: gather bf16, accumulate fp32, store bf16 y + fp32 acc ----
template <bool WRITE_Y, bool INIT_ACC>
__global__ void spmm_bf16(const int* __restrict__ rp, const int2* __restrict__ edges,
                          const unsigned short* __restrict__ xb, unsigned short* __restrict__ yb,
                          const float* __restrict__ e0, float* __restrict__ acc,
                          const float* __restrict__ att, int layer, int n_rows) {
    int w = (blockIdx.x * blockDim.x + threadIdx.x) >> 6;
    int lane = threadIdx.x & 63;
    if (w >= n_rows) return;
    float sum = row_gather_bf16(rp[w], rp[w + 1], edges, xb, lane);
    sum *= att[layer];
    size_t o = (size_t)w * DD + lane;
    if (WRITE_Y) yb[o] = f2bf(sum);
    if (INIT_ACC) acc[o] = e0[o] + sum;   // layer 1: acc = e0 + e1
    else          acc[o] += sum;
}

__global__ void set_bitmap(const int* __restrict__ users, unsigned char* __restrict__ bm, int B) {
    int i = blockIdx.x * blockDim.x + threadIdx.x;
    if (i < B) bm[users[i]] = 1;
}

// fused UI-SpMM + pair dot: one wave per batch element (all fp32)
__global__ void user_dot_kernel(const int* __restrict__ users, const int* __restrict__ items,
                                const int* __restrict__ rp, const int2* __restrict__ edges,
                                const float* __restrict__ acc, float* __restrict__ out, int B) {
    int w = (blockIdx.x * blockDim.x + threadIdx.x) >> 6;
    int lane = threadIdx.x & 63;
    if (w >= B) return;
    int u = users[w];
    float sum = row_gather_f32(rp[u], rp[u + 1], edges, acc, lane);
    float p = sum * acc[(size_t)items[w] * DD + lane];
    #pragma unroll
    for (int m = 32; m >= 1; m >>= 1) p += __shfl_xor(p, m, 64);
    if (lane == 0) out[w] = p * 0.0625f;   // (1/4 mean) each side
}

extern "C" void kernel_launch(void* const* d_in, const int* in_sizes, int n_in,
                              void* d_out, int out_size, void* d_ws, size_t ws_size,
                              hipStream_t stream) {
    const int*   users    = (const int*)d_in[0];
    const int*   items    = (const int*)d_in[1];
    const int*   ii_src   = (const int*)d_in[2];
    const int*   ii_dst   = (const int*)d_in[3];
    const float* ii_val   = (const float*)d_in[4];
    const int*   ui_src   = (const int*)d_in[5];
    const int*   ui_dst   = (const int*)d_in[6];
    const float* ui_val   = (const float*)d_in[7];
    const float* item_emb = (const float*)d_in[8];
    const float* att      = (const float*)d_in[9];

    const int E_ii = in_sizes[2];
    const int E_ui = in_sizes[5];
    const int B    = in_sizes[0];
    const int NB_ii = (MM + RPB - 1) / RPB;   // 391
    const int NB_ui = (UU + RPB - 1) / RPB;   // 196

    char* w = (char*)d_ws;
    unsigned short* xb0 = (unsigned short*)(w);             // 12.8 MB  (tmp low)
    unsigned short* y1  = (unsigned short*)(w + 12800000);  // 12.8 MB  (tmp high)
    unsigned short* y2  = (unsigned short*)(w + 25600000);  // 12.8 MB
    float* acc   = (float*)(w + 38400000);                  // 25.6 MB fp32
    int2*  edges = (int2*)(w + 64000000);                   // 25.6 MB
    int*   rp    = (int*)(w + 89600000);                    // (MM+2)*4
    int*   bcnt  = rp + MM + 2;
    int*   bbase = bcnt + 512;
    int*   bcur  = bbase + 514;
    unsigned char* bitmap = (unsigned char*)(bcur + 512);   // UU bytes

    int2* tmp = (int2*)w;    // 25.6 MB overlay on xb0+y1 (dead during builds)

    const int TB = 256;

    // ---- build item-item CSR ----
    hipMemsetAsync(bcnt, 0, 512 * sizeof(int), stream);
    {
        int chunk = (E_ii + 255) / 256;
        bucket_hist<<<256, TB, NB_ii * sizeof(int), stream>>>(ii_src, bcnt, E_ii, NB_ii, chunk, nullptr);
    }
    small_scan<<<1, 512, 0, stream>>>(bcnt, bbase, bcur, NB_ii);
    pass_a<<<(E_ii + CHUNK - 1) / CHUNK, TB, 0, stream>>>(ii_src, ii_dst, ii_val, bcur, tmp, E_ii, NB_ii, nullptr);
    pass_b<<<NB_ii, RPB, 0, stream>>>(bbase, tmp, edges, rp, MM, NB_ii);

    // ---- bf16 x0, then 3 propagation layers ----
    const int n4 = MM * DD / 4;
    conv_bf16<<<(n4 + TB - 1) / TB, TB, 0, stream>>>((const float4*)item_emb, (ushort4*)xb0, n4);
    const int ii_blocks = (MM * 64 + TB - 1) / TB;
    spmm_bf16<true,  true ><<<ii_blocks, TB, 0, stream>>>(rp, edges, xb0, y1, item_emb, acc, att, 0, MM);
    spmm_bf16<true,  false><<<ii_blocks, TB, 0, stream>>>(rp, edges, y1,  y2, nullptr,  acc, att, 1, MM);
    spmm_bf16<false, false><<<ii_blocks, TB, 0, stream>>>(rp, edges, y2,  nullptr, nullptr, acc, att, 2, MM);

    // ---- build batch-filtered user-item CSR (tmp region free again) ----
    hipMemsetAsync(bitmap, 0, UU, stream);
    set_bitmap<<<(B + TB - 1) / TB, TB, 0, stream>>>(users, bitmap, B);
    hipMemsetAsync(bcnt, 0, 512 * sizeof(int), stream);
    {
        int chunk = (E_ui + 255) / 256;
        bucket_hist<<<256, TB, NB_ui * sizeof(int), stream>>>(ui_src, bcnt, E_ui, NB_ui, chunk, bitmap);
    }
    small_scan<<<1, 512, 0, stream>>>(bcnt, bbase, bcur, NB_ui);
    pass_a<<<(E_ui + CHUNK - 1) / CHUNK, TB, 0, stream>>>(ui_src, ui_dst, ui_val, bcur, tmp, E_ui, NB_ui, bitmap);
    pass_b<<<NB_ui, RPB, 0, stream>>>(bbase, tmp, edges, rp, UU, NB_ui);

    // ---- fused user aggregation + pair dot (fp32) ----
    user_dot_kernel<<<(B * 64 + TB - 1) / TB, TB, 0, stream>>>(users, items, rp, edges, acc,
                                                               (float*)d_out, B);
}